// Round 1
// baseline (1903.091 us; speedup 1.0000x reference)
//
#include <hip/hip_runtime.h>
#include <hip/hip_bf16.h>
#include <cstdint>
#include <cstddef>

#define T_TOK 16384
#define DIM   1024
#define HID   4096
#define NE    8
#define NSLOT 33792   /* 32768 + 8*128 max padded slots */
#define BM 128
#define BN 128
#define BK 64

typedef __bf16 bf16_t;
typedef __bf16 bf16x8 __attribute__((ext_vector_type(8)));
typedef __bf16 bf16x4v __attribute__((ext_vector_type(4)));
typedef float  f32x4  __attribute__((ext_vector_type(4)));

// ---- async global->LDS, 16B per lane (CK idiom: int-roundtrip addrspace casts) ----
__device__ __forceinline__ void gload_lds16(const void* g, void* l) {
  __builtin_amdgcn_global_load_lds(
      (const __attribute__((address_space(1))) uint32_t*)(uintptr_t)g,
      (__attribute__((address_space(3))) uint32_t*)(uint32_t)(uintptr_t)l,
      16, 0, 0);
}

// meta layout (ints): [0..7]=counts, [8..15]=cursor, [16..24]=seg_base(9)

__global__ __launch_bounds__(256) void init_meta_kernel(int* __restrict__ ptok,
                                                        int* __restrict__ meta) {
  int i = blockIdx.x * 256 + threadIdx.x;
  if (i < NSLOT) ptok[i] = -1;
  if (i < 16) meta[i] = 0;
}

__global__ __launch_bounds__(256) void router_kernel(
    const float* __restrict__ x, const float* __restrict__ rw,
    float* __restrict__ logits, int* __restrict__ meta,
    int* __restrict__ te, float* __restrict__ tw) {
  const int lane = threadIdx.x & 63;
  const int t = blockIdx.x * 4 + (threadIdx.x >> 6);
  const float* xr = x + (size_t)t * DIM;
  float acc[NE] = {0.f,0.f,0.f,0.f,0.f,0.f,0.f,0.f};
  for (int d = lane; d < DIM; d += 64) {
    float xv = xr[d];
    float4 wa = *(const float4*)(rw + (size_t)d * NE);
    float4 wb = *(const float4*)(rw + (size_t)d * NE + 4);
    acc[0] += xv * wa.x; acc[1] += xv * wa.y; acc[2] += xv * wa.z; acc[3] += xv * wa.w;
    acc[4] += xv * wb.x; acc[5] += xv * wb.y; acc[6] += xv * wb.z; acc[7] += xv * wb.w;
  }
#pragma unroll
  for (int off = 32; off; off >>= 1) {
#pragma unroll
    for (int e = 0; e < NE; ++e) acc[e] += __shfl_down(acc[e], off);
  }
  if (lane == 0) {
    float m = acc[0];
#pragma unroll
    for (int e = 1; e < NE; ++e) m = fmaxf(m, acc[e]);
    float p[NE]; float s = 0.f;
#pragma unroll
    for (int e = 0; e < NE; ++e) { p[e] = expf(acc[e] - m); s += p[e]; }
    float inv = 1.0f / s;
    int e0 = 0;
#pragma unroll
    for (int e = 1; e < NE; ++e) if (p[e] > p[e0]) e0 = e;
    int e1 = (e0 == 0) ? 1 : 0;
#pragma unroll
    for (int e = 0; e < NE; ++e) if (e != e0 && p[e] > p[e1]) e1 = e;
#pragma unroll
    for (int e = 0; e < NE; ++e) logits[(size_t)t * NE + e] = acc[e];
    te[2 * t]     = e0;  te[2 * t + 1] = e1;
    tw[2 * t]     = p[e0] * inv;
    tw[2 * t + 1] = p[e1] * inv;
    atomicAdd(&meta[e0], 1);
    atomicAdd(&meta[e1], 1);
  }
}

__global__ void scan_kernel(int* __restrict__ meta) {
  if (threadIdx.x == 0 && blockIdx.x == 0) {
    int* seg = meta + 16;
    seg[0] = 0;
    for (int e = 0; e < NE; ++e) {
      seg[e + 1] = seg[e] + ((meta[e] + BM - 1) / BM) * BM;
      meta[8 + e] = 0;
    }
  }
}

__global__ __launch_bounds__(256) void scatter_kernel(
    const int* __restrict__ te, const float* __restrict__ tw,
    int* __restrict__ meta, int* __restrict__ ptok, float* __restrict__ pw) {
  int t = blockIdx.x * 256 + threadIdx.x;
#pragma unroll
  for (int k = 0; k < 2; ++k) {
    int e = te[2 * t + k];
    int pos = meta[16 + e] + atomicAdd(&meta[8 + e], 1);
    ptok[pos] = t;
    pw[pos] = tw[2 * t + k];
  }
}

__global__ __launch_bounds__(256) void cvt_kernel(const float* __restrict__ src,
                                                  bf16_t* __restrict__ dst, int n4) {
  for (int i = blockIdx.x * 256 + threadIdx.x; i < n4; i += gridDim.x * 256) {
    float4 v = ((const float4*)src)[i];
    bf16x4v o = { (bf16_t)v.x, (bf16_t)v.y, (bf16_t)v.z, (bf16_t)v.w };
    ((bf16x4v*)dst)[i] = o;
  }
}

// src: float [E][R][C]  ->  dst: bf16 [E][C][R]
__global__ __launch_bounds__(1024) void transpose_cvt_kernel(
    const float* __restrict__ src, bf16_t* __restrict__ dst, int R, int C) {
  __shared__ bf16_t tile[32][33];
  int e = blockIdx.z;
  int c0 = blockIdx.x * 32, r0 = blockIdx.y * 32;
  const float* s = src + (size_t)e * R * C;
  bf16_t* d = dst + (size_t)e * R * C;
  int tx = threadIdx.x, ty = threadIdx.y;
  tile[ty][tx] = (bf16_t)s[(size_t)(r0 + ty) * C + (c0 + tx)];
  __syncthreads();
  d[(size_t)(c0 + ty) * R + (r0 + tx)] = tile[tx][ty];
}

__global__ __launch_bounds__(256) void init_out_kernel(float* __restrict__ out,
                                                       const float* __restrict__ bias) {
  const int n4 = T_TOK * DIM / 4;
  for (int i = blockIdx.x * 256 + threadIdx.x; i < n4; i += gridDim.x * 256) {
    ((float4*)out)[i] = ((const float4*)bias)[i & 255];
  }
}

// ---------------- GEMM1: Hb = gelu(gather(Xb) @ W1t^T(view) + b1), bf16 out ---------------
__global__ __launch_bounds__(256) void gemm1_kernel(
    const bf16_t* __restrict__ Xb, const bf16_t* __restrict__ W1t,
    const float* __restrict__ b1, const int* __restrict__ ptok,
    const int* __restrict__ meta, bf16_t* __restrict__ Hb) {
  __shared__ __align__(16) bf16_t As[BM * BK];
  __shared__ __align__(16) bf16_t Bs[BN * BK];
  const int tid = threadIdx.x;
  const int lane = tid & 63;
  const int wave = tid >> 6;
  const int nt = blockIdx.x, mt = blockIdx.y;
  const int row0 = mt * BM;
  const int* seg = meta + 16;
  int e = 0;
#pragma unroll
  for (int k = 1; k < NE; ++k) if (row0 >= seg[k]) e = k;
  if (row0 - seg[e] >= meta[e]) return;  // fully-padded tile

  const bf16_t* Bbase = W1t + (size_t)e * HID * DIM + (size_t)nt * BN * DIM;
  size_t aoff[4]; size_t boff[4];
#pragma unroll
  for (int j = 0; j < 4; ++j) {
    int c = j * 256 + tid;
    int r = c >> 3;
    int cg = (c & 7) ^ (r & 7);          // fetch the chunk the swizzled read expects
    int tok = ptok[row0 + r];
    int tt = tok < 0 ? 0 : tok;
    aoff[j] = (size_t)tt * DIM + cg * 8;
    boff[j] = (size_t)r * DIM + cg * 8;
  }
  f32x4 acc[4][4] = {};
  const int wm = wave >> 1, wn = wave & 1;
  const int qr = lane >> 4;
  const int l16 = lane & 15;

  for (int k0 = 0; k0 < DIM; k0 += BK) {
#pragma unroll
    for (int j = 0; j < 4; ++j)
      gload_lds16(Xb + aoff[j] + k0, (char*)As + (j * 256 + tid) * 16);
#pragma unroll
    for (int j = 0; j < 4; ++j)
      gload_lds16(Bbase + boff[j] + k0, (char*)Bs + (j * 256 + tid) * 16);
    __syncthreads();
#pragma unroll
    for (int kk = 0; kk < 2; ++kk) {
      bf16x8 af[4], bfr[4];
#pragma unroll
      for (int mi = 0; mi < 4; ++mi) {
        int r = wm * 64 + mi * 16 + l16;
        int cg = (kk * 4 + qr) ^ (r & 7);
        af[mi] = *(const bf16x8*)((const char*)As + r * 128 + cg * 16);
      }
#pragma unroll
      for (int ni = 0; ni < 4; ++ni) {
        int r = wn * 64 + ni * 16 + l16;
        int cg = (kk * 4 + qr) ^ (r & 7);
        bfr[ni] = *(const bf16x8*)((const char*)Bs + r * 128 + cg * 16);
      }
#pragma unroll
      for (int mi = 0; mi < 4; ++mi)
#pragma unroll
        for (int ni = 0; ni < 4; ++ni)
          acc[mi][ni] = __builtin_amdgcn_mfma_f32_16x16x32_bf16(af[mi], bfr[ni], acc[mi][ni], 0, 0, 0);
    }
    __syncthreads();
  }
  // epilogue: + b1, exact gelu, bf16 store (pad rows store garbage-but-finite; masked later)
#pragma unroll
  for (int mi = 0; mi < 4; ++mi) {
    int rb = row0 + wm * 64 + mi * 16 + qr * 4;
#pragma unroll
    for (int ni = 0; ni < 4; ++ni) {
      int col = nt * BN + wn * 64 + ni * 16 + l16;
      float bv = b1[e * HID + col];
#pragma unroll
      for (int j = 0; j < 4; ++j) {
        float v = acc[mi][ni][j] + bv;
        float g = 0.5f * v * (1.0f + erff(v * 0.70710678118654752f));
        Hb[(size_t)(rb + j) * HID + col] = (bf16_t)g;
      }
    }
  }
}

// ---------------- GEMM2: out[tok] += w * (Hb @ W2t^T(view) + b2) ---------------
__global__ __launch_bounds__(256) void gemm2_kernel(
    const bf16_t* __restrict__ Hb, const bf16_t* __restrict__ W2t,
    const float* __restrict__ b2, const int* __restrict__ ptok,
    const float* __restrict__ pw, const int* __restrict__ meta,
    float* __restrict__ out) {
  __shared__ __align__(16) bf16_t As[BM * BK];
  __shared__ __align__(16) bf16_t Bs[BN * BK];
  const int tid = threadIdx.x;
  const int lane = tid & 63;
  const int wave = tid >> 6;
  const int nt = blockIdx.x, mt = blockIdx.y;
  const int row0 = mt * BM;
  const int* seg = meta + 16;
  int e = 0;
#pragma unroll
  for (int k = 1; k < NE; ++k) if (row0 >= seg[k]) e = k;
  if (row0 - seg[e] >= meta[e]) return;

  const bf16_t* Bbase = W2t + (size_t)e * DIM * HID + (size_t)nt * BN * HID;
  size_t aoff[4]; size_t boff[4];
#pragma unroll
  for (int j = 0; j < 4; ++j) {
    int c = j * 256 + tid;
    int r = c >> 3;
    int cg = (c & 7) ^ (r & 7);
    aoff[j] = (size_t)(row0 + r) * HID + cg * 8;
    boff[j] = (size_t)r * HID + cg * 8;
  }
  f32x4 acc[4][4] = {};
  const int wm = wave >> 1, wn = wave & 1;
  const int qr = lane >> 4;
  const int l16 = lane & 15;

  for (int k0 = 0; k0 < HID; k0 += BK) {
#pragma unroll
    for (int j = 0; j < 4; ++j)
      gload_lds16(Hb + aoff[j] + k0, (char*)As + (j * 256 + tid) * 16);
#pragma unroll
    for (int j = 0; j < 4; ++j)
      gload_lds16(Bbase + boff[j] + k0, (char*)Bs + (j * 256 + tid) * 16);
    __syncthreads();
#pragma unroll
    for (int kk = 0; kk < 2; ++kk) {
      bf16x8 af[4], bfr[4];
#pragma unroll
      for (int mi = 0; mi < 4; ++mi) {
        int r = wm * 64 + mi * 16 + l16;
        int cg = (kk * 4 + qr) ^ (r & 7);
        af[mi] = *(const bf16x8*)((const char*)As + r * 128 + cg * 16);
      }
#pragma unroll
      for (int ni = 0; ni < 4; ++ni) {
        int r = wn * 64 + ni * 16 + l16;
        int cg = (kk * 4 + qr) ^ (r & 7);
        bfr[ni] = *(const bf16x8*)((const char*)Bs + r * 128 + cg * 16);
      }
#pragma unroll
      for (int mi = 0; mi < 4; ++mi)
#pragma unroll
        for (int ni = 0; ni < 4; ++ni)
          acc[mi][ni] = __builtin_amdgcn_mfma_f32_16x16x32_bf16(af[mi], bfr[ni], acc[mi][ni], 0, 0, 0);
    }
    __syncthreads();
  }
#pragma unroll
  for (int mi = 0; mi < 4; ++mi) {
    int rb = row0 + wm * 64 + mi * 16 + qr * 4;
    int tk[4]; float wv[4];
#pragma unroll
    for (int j = 0; j < 4; ++j) { tk[j] = ptok[rb + j]; wv[j] = pw[rb + j]; }
#pragma unroll
    for (int ni = 0; ni < 4; ++ni) {
      int col = nt * BN + wn * 64 + ni * 16 + l16;
      float b2v = b2[e * DIM + col];
#pragma unroll
      for (int j = 0; j < 4; ++j) {
        if (tk[j] >= 0)
          atomicAdd(out + (size_t)tk[j] * DIM + col, wv[j] * (acc[mi][ni][j] + b2v));
      }
    }
  }
}

extern "C" void kernel_launch(void* const* d_in, const int* in_sizes, int n_in,
                              void* d_out, int out_size, void* d_ws, size_t ws_size,
                              hipStream_t stream) {
  const float* x    = (const float*)d_in[0];
  const float* rw   = (const float*)d_in[1];
  const float* w1   = (const float*)d_in[2];
  const float* b1   = (const float*)d_in[3];
  const float* w2   = (const float*)d_in[4];
  const float* b2   = (const float*)d_in[5];
  const float* bias = (const float*)d_in[6];
  float* out    = (float*)d_out;
  float* logits = out + (size_t)T_TOK * DIM;

  // workspace layout (bytes)
  const size_t XB_OFF  = 0;                      // bf16 [T][D]        33,554,432
  const size_t W1T_OFF = 33554432;               // bf16 [E][H][D]     67,108,864
  const size_t W2T_OFF = 100663296;              // bf16 [E][D][H]     67,108,864
  const size_t HB_OFF  = 167772160;              // bf16 [NSLOT][H]   276,824,064
  const size_t PT_OFF  = 444596224;              // int  [NSLOT]
  const size_t PW_OFF  = 444731392;              // f32  [NSLOT]
  const size_t TE_OFF  = 444866560;              // int  [T*2]
  const size_t TW_OFF  = 444997632;              // f32  [T*2]
  const size_t MT_OFF  = 445128704;              // int  [32]
  const size_t WS_NEEDED = MT_OFF + 128;
  if (ws_size < WS_NEEDED) return;  // will show as poison-fail; diagnosable

  char* ws = (char*)d_ws;
  bf16_t* Xb  = (bf16_t*)(ws + XB_OFF);
  bf16_t* W1t = (bf16_t*)(ws + W1T_OFF);
  bf16_t* W2t = (bf16_t*)(ws + W2T_OFF);
  bf16_t* Hb  = (bf16_t*)(ws + HB_OFF);
  int*    ptok= (int*)  (ws + PT_OFF);
  float*  pwv = (float*)(ws + PW_OFF);
  int*    te  = (int*)  (ws + TE_OFF);
  float*  tw  = (float*)(ws + TW_OFF);
  int*    meta= (int*)  (ws + MT_OFF);

  init_meta_kernel<<<NSLOT / 256, 256, 0, stream>>>(ptok, meta);
  router_kernel<<<T_TOK / 4, 256, 0, stream>>>(x, rw, logits, meta, te, tw);
  scan_kernel<<<1, 64, 0, stream>>>(meta);
  scatter_kernel<<<T_TOK / 256, 256, 0, stream>>>(te, tw, meta, ptok, pwv);
  cvt_kernel<<<2048, 256, 0, stream>>>(x, Xb, T_TOK * DIM / 4);
  transpose_cvt_kernel<<<dim3(HID / 32, DIM / 32, NE), dim3(32, 32), 0, stream>>>(w1, W1t, DIM, HID);
  transpose_cvt_kernel<<<dim3(DIM / 32, HID / 32, NE), dim3(32, 32), 0, stream>>>(w2, W2t, HID, DIM);
  init_out_kernel<<<2048, 256, 0, stream>>>(out, bias);
  gemm1_kernel<<<dim3(HID / BN, NSLOT / BM), 256, 0, stream>>>(Xb, W1t, b1, ptok, meta, Hb);
  gemm2_kernel<<<dim3(DIM / BN, NSLOT / BM), 256, 0, stream>>>(Hb, W2t, b2, ptok, pwv, meta, out);
}

// Round 2
// 1455.856 us; speedup vs baseline: 1.3072x; 1.3072x over previous
//
#include <hip/hip_runtime.h>
#include <hip/hip_bf16.h>
#include <cstdint>
#include <cstddef>

#define T_TOK 16384
#define DIM   1024
#define HID   4096
#define NE    8
#define NSLOT 34816   /* 32768 + 8*256 max padded slots (256-aligned segments) */
#define BK 64

typedef __bf16 bf16_t;
typedef __bf16 bf16x8 __attribute__((ext_vector_type(8)));
typedef __bf16 bf16x4v __attribute__((ext_vector_type(4)));
typedef float  f32x4  __attribute__((ext_vector_type(4)));

__device__ __forceinline__ void gload_lds16(const void* g, const void* l) {
  __builtin_amdgcn_global_load_lds(
      (const __attribute__((address_space(1))) uint32_t*)(uintptr_t)g,
      (__attribute__((address_space(3))) uint32_t*)(uint32_t)(uintptr_t)l,
      16, 0, 0);
}

// meta layout (ints): [0..7]=counts, [8..15]=cursor, [16..24]=seg_base(9)

__global__ __launch_bounds__(256) void init_meta_kernel(int* __restrict__ ptok,
                                                        int* __restrict__ meta) {
  int i = blockIdx.x * 256 + threadIdx.x;
  if (i < NSLOT) ptok[i] = -1;
  if (i < 16) meta[i] = 0;
}

__global__ __launch_bounds__(256) void router_kernel(
    const float* __restrict__ x, const float* __restrict__ rw,
    float* __restrict__ logits, int* __restrict__ meta,
    int* __restrict__ te, float* __restrict__ tw) {
  const int lane = threadIdx.x & 63;
  const int t = blockIdx.x * 4 + (threadIdx.x >> 6);
  const float* xr = x + (size_t)t * DIM;
  float acc[NE] = {0.f,0.f,0.f,0.f,0.f,0.f,0.f,0.f};
  for (int d = lane; d < DIM; d += 64) {
    float xv = xr[d];
    float4 wa = *(const float4*)(rw + (size_t)d * NE);
    float4 wb = *(const float4*)(rw + (size_t)d * NE + 4);
    acc[0] += xv * wa.x; acc[1] += xv * wa.y; acc[2] += xv * wa.z; acc[3] += xv * wa.w;
    acc[4] += xv * wb.x; acc[5] += xv * wb.y; acc[6] += xv * wb.z; acc[7] += xv * wb.w;
  }
#pragma unroll
  for (int off = 32; off; off >>= 1) {
#pragma unroll
    for (int e = 0; e < NE; ++e) acc[e] += __shfl_down(acc[e], off);
  }
  if (lane == 0) {
    float m = acc[0];
#pragma unroll
    for (int e = 1; e < NE; ++e) m = fmaxf(m, acc[e]);
    float p[NE]; float s = 0.f;
#pragma unroll
    for (int e = 0; e < NE; ++e) { p[e] = expf(acc[e] - m); s += p[e]; }
    float inv = 1.0f / s;
    int e0 = 0;
#pragma unroll
    for (int e = 1; e < NE; ++e) if (p[e] > p[e0]) e0 = e;
    int e1 = (e0 == 0) ? 1 : 0;
#pragma unroll
    for (int e = 0; e < NE; ++e) if (e != e0 && p[e] > p[e1]) e1 = e;
#pragma unroll
    for (int e = 0; e < NE; ++e) logits[(size_t)t * NE + e] = acc[e];
    te[2 * t]     = e0;  te[2 * t + 1] = e1;
    tw[2 * t]     = p[e0] * inv;
    tw[2 * t + 1] = p[e1] * inv;
    atomicAdd(&meta[e0], 1);
    atomicAdd(&meta[e1], 1);
  }
}

__global__ void scan_kernel(int* __restrict__ meta) {
  if (threadIdx.x == 0 && blockIdx.x == 0) {
    int* seg = meta + 16;
    seg[0] = 0;
    for (int e = 0; e < NE; ++e) {
      seg[e + 1] = seg[e] + ((meta[e] + 255) / 256) * 256;
      meta[8 + e] = 0;
    }
  }
}

__global__ __launch_bounds__(256) void scatter_kernel(
    const int* __restrict__ te, const float* __restrict__ tw,
    int* __restrict__ meta, int* __restrict__ ptok, float* __restrict__ pw) {
  int t = blockIdx.x * 256 + threadIdx.x;
#pragma unroll
  for (int k = 0; k < 2; ++k) {
    int e = te[2 * t + k];
    int pos = meta[16 + e] + atomicAdd(&meta[8 + e], 1);
    ptok[pos] = t;
    pw[pos] = tw[2 * t + k];
  }
}

__global__ __launch_bounds__(256) void cvt_kernel(const float* __restrict__ src,
                                                  bf16_t* __restrict__ dst, int n4) {
  for (int i = blockIdx.x * 256 + threadIdx.x; i < n4; i += gridDim.x * 256) {
    float4 v = ((const float4*)src)[i];
    bf16x4v o = { (bf16_t)v.x, (bf16_t)v.y, (bf16_t)v.z, (bf16_t)v.w };
    ((bf16x4v*)dst)[i] = o;
  }
}

// src: float [E][R][C]  ->  dst: bf16 [E][C][R]   (64x64 tiles, 256 thr, vectorized)
__global__ __launch_bounds__(256) void transpose_cvt_kernel(
    const float* __restrict__ src, bf16_t* __restrict__ dst, int R, int C) {
  __shared__ bf16_t tile[64][68];
  int e = blockIdx.z;
  int c0 = blockIdx.x * 64, r0 = blockIdx.y * 64;
  const float* s = src + (size_t)e * R * C;
  bf16_t* d = dst + (size_t)e * R * C;
  int tx = threadIdx.x & 15, ty = threadIdx.x >> 4;
#pragma unroll
  for (int i = 0; i < 4; ++i) {
    int r = ty + i * 16;
    float4 v = *(const float4*)(s + (size_t)(r0 + r) * C + c0 + tx * 4);
    tile[r][tx * 4 + 0] = (bf16_t)v.x;
    tile[r][tx * 4 + 1] = (bf16_t)v.y;
    tile[r][tx * 4 + 2] = (bf16_t)v.z;
    tile[r][tx * 4 + 3] = (bf16_t)v.w;
  }
  __syncthreads();
#pragma unroll
  for (int i = 0; i < 4; ++i) {
    int cc = ty + i * 16;
    bf16x4v o = { tile[tx * 4 + 0][cc], tile[tx * 4 + 1][cc],
                  tile[tx * 4 + 2][cc], tile[tx * 4 + 3][cc] };
    *(bf16x4v*)(d + (size_t)(c0 + cc) * R + r0 + tx * 4) = o;
  }
}

__global__ __launch_bounds__(256) void init_out_kernel(float* __restrict__ out,
                                                       const float* __restrict__ bias) {
  const int n4 = T_TOK * DIM / 4;
  for (int i = blockIdx.x * 256 + threadIdx.x; i < n4; i += gridDim.x * 256) {
    ((float4*)out)[i] = ((const float4*)bias)[i & 255];
  }
}

// ===================== 256x256 8-wave 4-phase pipelined GEMM bodies =====================
// LDS: A regions [buf][half] 128x64 bf16 = 16KB each at (buf*2+h)*16384; B at +65536.
// Swizzle (verified round 1): LDS (row, chunk c) holds source chunk c^(row&7); row stride 128B.

#define GEMM_PRE()                                                              \
  const int tid = threadIdx.x;                                                  \
  const int lane = tid & 63;                                                    \
  const int wave = tid >> 6;                                                    \
  const int wm = wave >> 2, wn = wave & 3;                                      \
  const int qr = lane >> 4, l16 = lane & 15;                                    \
  const uint32_t aRd0 = (wm * 64 + l16) * 128 + ((qr ^ (l16 & 7)) * 16);        \
  const uint32_t aRd1 = (wm * 64 + l16) * 128 + (((4 + qr) ^ (l16 & 7)) * 16);  \
  const uint32_t bRd0 = (wn * 32 + l16) * 128 + ((qr ^ (l16 & 7)) * 16);        \
  const uint32_t bRd1 = (wn * 32 + l16) * 128 + (((4 + qr) ^ (l16 & 7)) * 16);

#define STAGE_A(H, P, KT) {                                                     \
  const char* _d = lds + ((P) * 2 + (H)) * 16384 + tid * 16;                    \
  gload_lds16(aSrc[H][0] + (size_t)(KT) * BK, _d);                              \
  gload_lds16(aSrc[H][1] + (size_t)(KT) * BK, _d + 8192); }

#define STAGE_B(H, P, KT) {                                                     \
  const char* _d = lds + 65536 + ((P) * 2 + (H)) * 16384 + tid * 16;            \
  gload_lds16(bSrc[H][0] + (size_t)(KT) * BK, _d);                              \
  gload_lds16(bSrc[H][1] + (size_t)(KT) * BK, _d + 8192); }

#define LOAD_AF(AH) {                                                           \
  const char* _p = lds + (cur * 2 + (AH)) * 16384;                              \
  _Pragma("unroll")                                                             \
  for (int mi = 0; mi < 4; ++mi) {                                              \
    af[mi][0] = *(const bf16x8*)(_p + aRd0 + mi * 2048);                        \
    af[mi][1] = *(const bf16x8*)(_p + aRd1 + mi * 2048); } }

#define LOAD_BF(BH, BF) {                                                       \
  const char* _p = lds + 65536 + (cur * 2 + (BH)) * 16384;                      \
  _Pragma("unroll")                                                             \
  for (int ni = 0; ni < 2; ++ni) {                                              \
    BF[ni][0] = *(const bf16x8*)(_p + bRd0 + ni * 2048);                        \
    BF[ni][1] = *(const bf16x8*)(_p + bRd1 + ni * 2048); } }

#define MFMA_PH(AH, BH, BF)                                                     \
  __builtin_amdgcn_s_setprio(1);                                                \
  _Pragma("unroll")                                                             \
  for (int mi = 0; mi < 4; ++mi)                                                \
  _Pragma("unroll")                                                             \
  for (int ni = 0; ni < 2; ++ni) {                                              \
    acc[AH][BH][mi][ni] = __builtin_amdgcn_mfma_f32_16x16x32_bf16(              \
        af[mi][0], BF[ni][0], acc[AH][BH][mi][ni], 0, 0, 0);                    \
    acc[AH][BH][mi][ni] = __builtin_amdgcn_mfma_f32_16x16x32_bf16(              \
        af[mi][1], BF[ni][1], acc[AH][BH][mi][ni], 0, 0, 0);                    \
  }                                                                             \
  __builtin_amdgcn_s_setprio(0);                                                \
  __builtin_amdgcn_sched_barrier(0);

#define BAR_A()                                                                 \
  __builtin_amdgcn_s_barrier();                                                 \
  asm volatile("s_waitcnt lgkmcnt(0)" ::: "memory");                            \
  __builtin_amdgcn_sched_barrier(0);

#define KLOOP(NT)                                                               \
  STAGE_A(0, 0, 0); STAGE_B(0, 0, 0); STAGE_B(1, 0, 0); STAGE_A(1, 0, 0);       \
  STAGE_A(0, 1, 1 < (NT) ? 1 : (NT)-1); STAGE_B(0, 1, 1 < (NT) ? 1 : (NT)-1);   \
  asm volatile("s_waitcnt vmcnt(6)" ::: "memory");                              \
  __builtin_amdgcn_s_barrier();                                                 \
  for (int t = 0; t < (NT); ++t) {                                              \
    const int cur = t & 1, nxt = cur ^ 1;                                       \
    const int kt1 = (t + 1 < (NT)) ? t + 1 : (NT) - 1;                          \
    const int kt2 = (t + 2 < (NT)) ? t + 2 : (NT) - 1;                          \
    /* ph1: quadrant (A0,B0) */                                                 \
    LOAD_AF(0); LOAD_BF(0, bf0);                                                \
    STAGE_B(1, nxt, kt1);                                                       \
    BAR_A();                                                                    \
    MFMA_PH(0, 0, bf0);                                                         \
    __builtin_amdgcn_s_barrier();                                               \
    /* ph2: quadrant (A0,B1) */                                                 \
    LOAD_BF(1, bf1);                                                            \
    STAGE_A(1, nxt, kt1);                                                       \
    BAR_A();                                                                    \
    MFMA_PH(0, 1, bf1);                                                         \
    asm volatile("s_waitcnt vmcnt(8)" ::: "memory");                            \
    __builtin_amdgcn_s_barrier();                                               \
    /* ph3: quadrant (A1,B0) */                                                 \
    LOAD_AF(1);                                                                 \
    STAGE_A(0, cur, kt2);                                                       \
    BAR_A();                                                                    \
    MFMA_PH(1, 0, bf0);                                                         \
    __builtin_amdgcn_s_barrier();                                               \
    /* ph4: quadrant (A1,B1) */                                                 \
    STAGE_B(0, cur, kt2);                                                       \
    BAR_A();                                                                    \
    MFMA_PH(1, 1, bf1);                                                         \
    asm volatile("s_waitcnt vmcnt(6)" ::: "memory");                            \
    __builtin_amdgcn_s_barrier();                                               \
  }

// ---------------- GEMM1: Hb = gelu(gather(Xb) @ W1t^T + b1) ----------------
__global__ __launch_bounds__(512, 2) void gemm1_kernel(
    const bf16_t* __restrict__ Xb, const bf16_t* __restrict__ W1t,
    const float* __restrict__ b1, const int* __restrict__ ptok,
    const int* __restrict__ meta, bf16_t* __restrict__ Hb) {
  __shared__ __align__(16) char lds[131072];
  GEMM_PRE();
  // XCD swizzle: nwg = 16*136 = 2176, cpx = 272
  int orig = blockIdx.y * 16 + blockIdx.x;
  int wg = (orig & 7) * 272 + (orig >> 3);
  const int mt = wg >> 4, nt = wg & 15;
  const int row0 = mt * 256;
  const int* seg = meta + 16;
  int e = 0;
#pragma unroll
  for (int k = 1; k < NE; ++k) if (row0 >= seg[k]) e = k;
  if (row0 - seg[e] >= meta[e]) return;

  const bf16_t* aSrc[2][2];
  const bf16_t* bSrc[2][2];
#pragma unroll
  for (int h = 0; h < 2; ++h)
#pragma unroll
    for (int j = 0; j < 2; ++j) {
      int idx = j * 512 + tid;
      int rl = idx >> 3, c = idx & 7;
      int cs = c ^ (rl & 7);
      int tok = ptok[row0 + h * 128 + rl];
      if (tok < 0) tok = 0;
      aSrc[h][j] = Xb + (size_t)tok * DIM + cs * 8;
      int brow = nt * 256 + h * 128 + rl;
      bSrc[h][j] = W1t + (size_t)e * HID * DIM + (size_t)brow * DIM + cs * 8;
    }

  f32x4 acc[2][2][4][2] = {};
  bf16x8 af[4][2], bf0[2][2], bf1[2][2];
  KLOOP(DIM / BK);

  // epilogue: + b1, exact gelu, bf16 store
#pragma unroll
  for (int BH_ = 0; BH_ < 2; ++BH_)
#pragma unroll
  for (int ni = 0; ni < 2; ++ni) {
    int col = nt * 256 + BH_ * 128 + wn * 32 + ni * 16 + l16;
    float bv = b1[e * HID + col];
#pragma unroll
    for (int AH_ = 0; AH_ < 2; ++AH_)
#pragma unroll
    for (int mi = 0; mi < 4; ++mi) {
      int r = row0 + AH_ * 128 + wm * 64 + mi * 16 + qr * 4;
#pragma unroll
      for (int j = 0; j < 4; ++j) {
        float v = acc[AH_][BH_][mi][ni][j] + bv;
        float g = 0.5f * v * (1.0f + erff(v * 0.70710678118654752f));
        Hb[(size_t)(r + j) * HID + col] = (bf16_t)g;
      }
    }
  }
}

// ---------------- GEMM2: out[tok] += w * (Hb @ W2t^T + b2) ----------------
__global__ __launch_bounds__(512, 2) void gemm2_kernel(
    const bf16_t* __restrict__ Hb, const bf16_t* __restrict__ W2t,
    const float* __restrict__ b2, const int* __restrict__ ptok,
    const float* __restrict__ pw, const int* __restrict__ meta,
    float* __restrict__ out) {
  __shared__ __align__(16) char lds[131072];
  GEMM_PRE();
  // XCD swizzle: nwg = 4*136 = 544, cpx = 68
  int orig = blockIdx.y * 4 + blockIdx.x;
  int wg = (orig & 7) * 68 + (orig >> 3);
  const int mt = wg >> 2, nt = wg & 3;
  const int row0 = mt * 256;
  const int* seg = meta + 16;
  int e = 0;
#pragma unroll
  for (int k = 1; k < NE; ++k) if (row0 >= seg[k]) e = k;
  if (row0 - seg[e] >= meta[e]) return;

  const bf16_t* aSrc[2][2];
  const bf16_t* bSrc[2][2];
#pragma unroll
  for (int h = 0; h < 2; ++h)
#pragma unroll
    for (int j = 0; j < 2; ++j) {
      int idx = j * 512 + tid;
      int rl = idx >> 3, c = idx & 7;
      int cs = c ^ (rl & 7);
      aSrc[h][j] = Hb + (size_t)(row0 + h * 128 + rl) * HID + cs * 8;
      int brow = nt * 256 + h * 128 + rl;
      bSrc[h][j] = W2t + (size_t)e * DIM * HID + (size_t)brow * HID + cs * 8;
    }

  f32x4 acc[2][2][4][2] = {};
  bf16x8 af[4][2], bf0[2][2], bf1[2][2];
  KLOOP(HID / BK);

  // epilogue: gather-combine with atomics
  float bv2[2][2];
#pragma unroll
  for (int BH_ = 0; BH_ < 2; ++BH_)
#pragma unroll
  for (int ni = 0; ni < 2; ++ni)
    bv2[BH_][ni] = b2[e * DIM + nt * 256 + BH_ * 128 + wn * 32 + ni * 16 + l16];

#pragma unroll
  for (int AH_ = 0; AH_ < 2; ++AH_)
#pragma unroll
  for (int mi = 0; mi < 4; ++mi) {
    int r = row0 + AH_ * 128 + wm * 64 + mi * 16 + qr * 4;
    int tk[4]; float wv[4];
#pragma unroll
    for (int j = 0; j < 4; ++j) { tk[j] = ptok[r + j]; wv[j] = pw[r + j]; }
#pragma unroll
    for (int BH_ = 0; BH_ < 2; ++BH_)
#pragma unroll
    for (int ni = 0; ni < 2; ++ni) {
      int col = nt * 256 + BH_ * 128 + wn * 32 + ni * 16 + l16;
#pragma unroll
      for (int j = 0; j < 4; ++j) {
        if (tk[j] >= 0)
          atomicAdd(out + (size_t)tk[j] * DIM + col,
                    wv[j] * (acc[AH_][BH_][mi][ni][j] + bv2[BH_][ni]));
      }
    }
  }
}

extern "C" void kernel_launch(void* const* d_in, const int* in_sizes, int n_in,
                              void* d_out, int out_size, void* d_ws, size_t ws_size,
                              hipStream_t stream) {
  const float* x    = (const float*)d_in[0];
  const float* rw   = (const float*)d_in[1];
  const float* w1   = (const float*)d_in[2];
  const float* b1   = (const float*)d_in[3];
  const float* w2   = (const float*)d_in[4];
  const float* b2   = (const float*)d_in[5];
  const float* bias = (const float*)d_in[6];
  float* out    = (float*)d_out;
  float* logits = out + (size_t)T_TOK * DIM;

  // workspace layout (bytes). W1t/W2t OVERLAY (transpose w2 after gemm1).
  const size_t XB_OFF = 0;                         // bf16 [T][D]      33,554,432
  const size_t WT_OFF = 33554432;                  // bf16 [E][*][*]   67,108,864 (shared)
  const size_t HB_OFF = 100663296;                 // bf16 [NSLOT][H] 285,212,672
  const size_t PT_OFF = 385875968;                 // int  [NSLOT]
  const size_t PW_OFF = 386015232;                 // f32  [NSLOT]
  const size_t TE_OFF = 386154496;                 // int  [T*2]
  const size_t TW_OFF = 386285568;                 // f32  [T*2]
  const size_t MT_OFF = 386416640;                 // int  [32]
  const size_t WS_NEEDED = MT_OFF + 128;
  if (ws_size < WS_NEEDED) return;

  char* ws = (char*)d_ws;
  bf16_t* Xb  = (bf16_t*)(ws + XB_OFF);
  bf16_t* Wt  = (bf16_t*)(ws + WT_OFF);
  bf16_t* Hb  = (bf16_t*)(ws + HB_OFF);
  int*    ptok= (int*)  (ws + PT_OFF);
  float*  pwv = (float*)(ws + PW_OFF);
  int*    te  = (int*)  (ws + TE_OFF);
  float*  tw  = (float*)(ws + TW_OFF);
  int*    meta= (int*)  (ws + MT_OFF);

  init_meta_kernel<<<NSLOT / 256, 256, 0, stream>>>(ptok, meta);
  router_kernel<<<T_TOK / 4, 256, 0, stream>>>(x, rw, logits, meta, te, tw);
  scan_kernel<<<1, 64, 0, stream>>>(meta);
  scatter_kernel<<<T_TOK / 256, 256, 0, stream>>>(te, tw, meta, ptok, pwv);
  cvt_kernel<<<2048, 256, 0, stream>>>(x, Xb, T_TOK * DIM / 4);
  // W1 transpose: [E][D][H] -> [E][H][D]
  transpose_cvt_kernel<<<dim3(HID / 64, DIM / 64, NE), 256, 0, stream>>>(w1, Wt, DIM, HID);
  init_out_kernel<<<2048, 256, 0, stream>>>(out, bias);
  gemm1_kernel<<<dim3(16, NSLOT / 256), 512, 0, stream>>>(Xb, Wt, b1, ptok, meta, Hb);
  // W2 transpose into the SAME buffer (gemm1 done reading W1t; stream serializes)
  transpose_cvt_kernel<<<dim3(DIM / 64, HID / 64, NE), 256, 0, stream>>>(w2, Wt, HID, DIM);
  gemm2_kernel<<<dim3(4, NSLOT / 256), 512, 0, stream>>>(Hb, Wt, b2, ptok, pwv, meta, out);
}

// Round 3
// 1441.548 us; speedup vs baseline: 1.3202x; 1.0099x over previous
//
#include <hip/hip_runtime.h>
#include <hip/hip_bf16.h>
#include <cstdint>
#include <cstddef>

#define T_TOK 16384
#define DIM   1024
#define HID   4096
#define NE    8
#define NSLOT 34816   /* 32768 + 8*256 max padded slots (256-aligned segments) */
#define BK 64

typedef __bf16 bf16_t;
typedef __bf16 bf16x8 __attribute__((ext_vector_type(8)));
typedef __bf16 bf16x4v __attribute__((ext_vector_type(4)));
typedef float  f32x4  __attribute__((ext_vector_type(4)));

__device__ __forceinline__ void gload_lds16(const void* g, const void* l) {
  __builtin_amdgcn_global_load_lds(
      (const __attribute__((address_space(1))) uint32_t*)(uintptr_t)g,
      (__attribute__((address_space(3))) uint32_t*)(uint32_t)(uintptr_t)l,
      16, 0, 0);
}

// meta layout (ints): [0..7]=counts, [8..15]=cursor, [16..24]=seg_base(9)

__global__ __launch_bounds__(256) void init_meta_kernel(int* __restrict__ ptok,
                                                        int* __restrict__ meta) {
  int i = blockIdx.x * 256 + threadIdx.x;
  if (i < NSLOT) ptok[i] = -1;
  if (i < 16) meta[i] = 0;
}

// router + fused f32->bf16 conversion of x into Xb
__global__ __launch_bounds__(256) void router_kernel(
    const float* __restrict__ x, const float* __restrict__ rw,
    float* __restrict__ logits, int* __restrict__ meta,
    int* __restrict__ te, float* __restrict__ tw, bf16_t* __restrict__ Xb) {
  const int lane = threadIdx.x & 63;
  const int t = blockIdx.x * 4 + (threadIdx.x >> 6);
  const float* xr = x + (size_t)t * DIM;
  float acc[NE] = {0.f,0.f,0.f,0.f,0.f,0.f,0.f,0.f};
  for (int d = lane; d < DIM; d += 64) {
    float xv = xr[d];
    Xb[(size_t)t * DIM + d] = (bf16_t)xv;
    float4 wa = *(const float4*)(rw + (size_t)d * NE);
    float4 wb = *(const float4*)(rw + (size_t)d * NE + 4);
    acc[0] += xv * wa.x; acc[1] += xv * wa.y; acc[2] += xv * wa.z; acc[3] += xv * wa.w;
    acc[4] += xv * wb.x; acc[5] += xv * wb.y; acc[6] += xv * wb.z; acc[7] += xv * wb.w;
  }
#pragma unroll
  for (int off = 32; off; off >>= 1) {
#pragma unroll
    for (int e = 0; e < NE; ++e) acc[e] += __shfl_down(acc[e], off);
  }
  if (lane == 0) {
    float m = acc[0];
#pragma unroll
    for (int e = 1; e < NE; ++e) m = fmaxf(m, acc[e]);
    float p[NE]; float s = 0.f;
#pragma unroll
    for (int e = 0; e < NE; ++e) { p[e] = expf(acc[e] - m); s += p[e]; }
    float inv = 1.0f / s;
    int e0 = 0;
#pragma unroll
    for (int e = 1; e < NE; ++e) if (p[e] > p[e0]) e0 = e;
    int e1 = (e0 == 0) ? 1 : 0;
#pragma unroll
    for (int e = 0; e < NE; ++e) if (e != e0 && p[e] > p[e1]) e1 = e;
#pragma unroll
    for (int e = 0; e < NE; ++e) logits[(size_t)t * NE + e] = acc[e];
    te[2 * t]     = e0;  te[2 * t + 1] = e1;
    tw[2 * t]     = p[e0] * inv;
    tw[2 * t + 1] = p[e1] * inv;
    atomicAdd(&meta[e0], 1);
    atomicAdd(&meta[e1], 1);
  }
}

__global__ void scan_kernel(int* __restrict__ meta) {
  if (threadIdx.x == 0 && blockIdx.x == 0) {
    int* seg = meta + 16;
    seg[0] = 0;
    for (int e = 0; e < NE; ++e) {
      seg[e + 1] = seg[e] + ((meta[e] + 255) / 256) * 256;
      meta[8 + e] = 0;
    }
  }
}

__global__ __launch_bounds__(256) void scatter_kernel(
    const int* __restrict__ te, const float* __restrict__ tw,
    int* __restrict__ meta, int* __restrict__ ptok, float* __restrict__ pw) {
  int t = blockIdx.x * 256 + threadIdx.x;
#pragma unroll
  for (int k = 0; k < 2; ++k) {
    int e = te[2 * t + k];
    int pos = meta[16 + e] + atomicAdd(&meta[8 + e], 1);
    ptok[pos] = t;
    pw[pos] = tw[2 * t + k];
  }
}

// src: float [E][R][C]  ->  dst: bf16 [E][C][R]   (64x64 tiles, 256 thr, vectorized)
__global__ __launch_bounds__(256) void transpose_cvt_kernel(
    const float* __restrict__ src, bf16_t* __restrict__ dst, int R, int C) {
  __shared__ bf16_t tile[64][68];
  int e = blockIdx.z;
  int c0 = blockIdx.x * 64, r0 = blockIdx.y * 64;
  const float* s = src + (size_t)e * R * C;
  bf16_t* d = dst + (size_t)e * R * C;
  int tx = threadIdx.x & 15, ty = threadIdx.x >> 4;
#pragma unroll
  for (int i = 0; i < 4; ++i) {
    int r = ty + i * 16;
    float4 v = *(const float4*)(s + (size_t)(r0 + r) * C + c0 + tx * 4);
    tile[r][tx * 4 + 0] = (bf16_t)v.x;
    tile[r][tx * 4 + 1] = (bf16_t)v.y;
    tile[r][tx * 4 + 2] = (bf16_t)v.z;
    tile[r][tx * 4 + 3] = (bf16_t)v.w;
  }
  __syncthreads();
#pragma unroll
  for (int i = 0; i < 4; ++i) {
    int cc = ty + i * 16;
    bf16x4v o = { tile[tx * 4 + 0][cc], tile[tx * 4 + 1][cc],
                  tile[tx * 4 + 2][cc], tile[tx * 4 + 3][cc] };
    *(bf16x4v*)(d + (size_t)(c0 + cc) * R + r0 + tx * 4) = o;
  }
}

__global__ __launch_bounds__(256) void init_out_kernel(float* __restrict__ out,
                                                       const float* __restrict__ bias) {
  const int n4 = T_TOK * DIM / 4;
  for (int i = blockIdx.x * 256 + threadIdx.x; i < n4; i += gridDim.x * 256) {
    ((float4*)out)[i] = ((const float4*)bias)[i & 255];
  }
}

// ============ 256x256 8-wave pipelined GEMM: A ring 3-deep, B 2-deep ============
// LDS 160KiB: A stage s at s*32768 (s=0..2), halves +h*16384.
//             B stage p at 98304 + p*32768 (p=0..1), halves +h*16384.
// Swizzle (verified r1/r2): LDS (row, chunk c) holds source chunk c^(row&7).

#define GEMM_PRE()                                                              \
  const int tid = threadIdx.x;                                                  \
  const int lane = tid & 63;                                                    \
  const int wave = tid >> 6;                                                    \
  const int wm = wave >> 2, wn = wave & 3;                                      \
  const int qr = lane >> 4, l16 = lane & 15;                                    \
  const uint32_t aRd0 = (wm * 64 + l16) * 128 + ((qr ^ (l16 & 7)) * 16);        \
  const uint32_t aRd1 = (wm * 64 + l16) * 128 + (((4 + qr) ^ (l16 & 7)) * 16);  \
  const uint32_t bRd0 = (wn * 32 + l16) * 128 + ((qr ^ (l16 & 7)) * 16);        \
  const uint32_t bRd1 = (wn * 32 + l16) * 128 + (((4 + qr) ^ (l16 & 7)) * 16);  \
  uint32_t aB0 = 0, aB1 = 32768, aB2 = 65536;

#define STAGE_Ax(BASE, H, KT) {                                                 \
  const char* _d = lds + (BASE) + (H) * 16384 + tid * 16;                       \
  gload_lds16(aSrc[H][0] + (size_t)(KT) * BK, _d);                              \
  gload_lds16(aSrc[H][1] + (size_t)(KT) * BK, _d + 8192); }

#define STAGE_Bx(H, P2, KT) {                                                   \
  const char* _d = lds + 98304 + (P2) * 32768 + (H) * 16384 + tid * 16;         \
  gload_lds16(bSrc[H][0] + (size_t)(KT) * BK, _d);                              \
  gload_lds16(bSrc[H][1] + (size_t)(KT) * BK, _d + 8192); }

#define LOAD_AFx(AH) {                                                          \
  const char* _p = lds + aB0 + (AH) * 16384;                                    \
  _Pragma("unroll")                                                             \
  for (int mi = 0; mi < 4; ++mi) {                                              \
    af[mi][0] = *(const bf16x8*)(_p + aRd0 + mi * 2048);                        \
    af[mi][1] = *(const bf16x8*)(_p + aRd1 + mi * 2048); } }

#define LOAD_BFx(BH, BF, P) {                                                   \
  const char* _p = lds + 98304 + (P) * 32768 + (BH) * 16384;                    \
  _Pragma("unroll")                                                             \
  for (int ni = 0; ni < 2; ++ni) {                                              \
    BF[ni][0] = *(const bf16x8*)(_p + bRd0 + ni * 2048);                        \
    BF[ni][1] = *(const bf16x8*)(_p + bRd1 + ni * 2048); } }

#define MFMA_PH(AH, BH, BF)                                                     \
  __builtin_amdgcn_s_setprio(1);                                                \
  _Pragma("unroll")                                                             \
  for (int mi = 0; mi < 4; ++mi)                                                \
  _Pragma("unroll")                                                             \
  for (int ni = 0; ni < 2; ++ni) {                                              \
    acc[AH][BH][mi][ni] = __builtin_amdgcn_mfma_f32_16x16x32_bf16(              \
        af[mi][0], BF[ni][0], acc[AH][BH][mi][ni], 0, 0, 0);                    \
    acc[AH][BH][mi][ni] = __builtin_amdgcn_mfma_f32_16x16x32_bf16(              \
        af[mi][1], BF[ni][1], acc[AH][BH][mi][ni], 0, 0, 0);                    \
  }                                                                             \
  __builtin_amdgcn_s_setprio(0);                                                \
  __builtin_amdgcn_sched_barrier(0);

#define TILE_BODY(TT, P, NT)                                                    \
  {                                                                             \
    const int kt1 = ((TT) + 1 < (NT)) ? (TT) + 1 : (NT) - 1;                    \
    const int kt2 = ((TT) + 2 < (NT)) ? (TT) + 2 : (NT) - 1;                    \
    /* ph1 */                                                                   \
    LOAD_AFx(0);                                                                \
    LOAD_BFx(0, bf0, P);                                                        \
    STAGE_Bx(0, (P) ^ 1, kt1);                                                  \
    asm volatile("s_waitcnt lgkmcnt(8)" ::: "memory");                          \
    __builtin_amdgcn_s_barrier();                                               \
    asm volatile("s_waitcnt lgkmcnt(0)" ::: "memory");                          \
    __builtin_amdgcn_sched_barrier(0);                                          \
    MFMA_PH(0, 0, bf0);                                                         \
    asm volatile("s_waitcnt vmcnt(6)" ::: "memory");                            \
    __builtin_amdgcn_s_barrier();                                               \
    /* ph2 */                                                                   \
    LOAD_BFx(1, bf1, P);                                                        \
    STAGE_Bx(1, (P) ^ 1, kt1);                                                  \
    __builtin_amdgcn_s_barrier();                                               \
    asm volatile("s_waitcnt lgkmcnt(0)" ::: "memory");                          \
    __builtin_amdgcn_sched_barrier(0);                                          \
    MFMA_PH(0, 1, bf1);                                                         \
    __builtin_amdgcn_s_barrier();                                               \
    /* ph3 */                                                                   \
    LOAD_AFx(1);                                                                \
    STAGE_Ax(aB2, 0, kt2);                                                      \
    __builtin_amdgcn_s_barrier();                                               \
    asm volatile("s_waitcnt lgkmcnt(0)" ::: "memory");                          \
    __builtin_amdgcn_sched_barrier(0);                                          \
    MFMA_PH(1, 0, bf0);                                                         \
    __builtin_amdgcn_s_barrier();                                               \
    /* ph4 (register-only MFMA: no pre-barrier needed) */                       \
    STAGE_Ax(aB2, 1, kt2);                                                      \
    MFMA_PH(1, 1, bf1);                                                         \
    asm volatile("s_waitcnt vmcnt(6)" ::: "memory");                            \
    __builtin_amdgcn_s_barrier();                                               \
    uint32_t _tmp = aB0; aB0 = aB1; aB1 = aB2; aB2 = _tmp;                      \
  }

#define KLOOP(NT)                                                               \
  STAGE_Ax(aB0, 0, 0); STAGE_Ax(aB0, 1, 0);                                     \
  STAGE_Ax(aB1, 0, 1 < (NT) ? 1 : 0); STAGE_Ax(aB1, 1, 1 < (NT) ? 1 : 0);       \
  STAGE_Bx(0, 0, 0); STAGE_Bx(1, 0, 0);                                         \
  asm volatile("s_waitcnt vmcnt(0)" ::: "memory");                              \
  __builtin_amdgcn_s_barrier();                                                 \
  for (int t = 0; t < (NT); t += 2) {                                           \
    TILE_BODY(t, 0, NT);                                                        \
    TILE_BODY(t + 1, 1, NT);                                                    \
  }

// ---------------- GEMM1: Hb = gelu(gather(Xb) @ W1t^T + b1) ----------------
__global__ __launch_bounds__(512, 2) void gemm1_kernel(
    const bf16_t* __restrict__ Xb, const bf16_t* __restrict__ W1t,
    const float* __restrict__ b1, const int* __restrict__ ptok,
    const int* __restrict__ meta, bf16_t* __restrict__ Hb) {
  __shared__ __align__(16) char lds[163840];
  GEMM_PRE();
  // chunked XCD swizzle, nt-major (each XCD owns 2 nt columns; B slab 1MB -> L2)
  int b = blockIdx.x;                       // 2176 blocks
  int g = (b & 7) * 272 + (b >> 3);
  const int nt = g / 136, mt = g - nt * 136;
  const int row0 = mt * 256;
  const int* seg = meta + 16;
  int e = 0;
#pragma unroll
  for (int k = 1; k < NE; ++k) if (row0 >= seg[k]) e = k;
  if (row0 - seg[e] >= meta[e]) return;

  const bf16_t* aSrc[2][2];
  const bf16_t* bSrc[2][2];
#pragma unroll
  for (int h = 0; h < 2; ++h)
#pragma unroll
    for (int j = 0; j < 2; ++j) {
      int idx = j * 512 + tid;
      int rl = idx >> 3, c = idx & 7;
      int cs = c ^ (rl & 7);
      int tok = ptok[row0 + h * 128 + rl];
      if (tok < 0) tok = 0;
      aSrc[h][j] = Xb + (size_t)tok * DIM + cs * 8;
      int brow = nt * 256 + h * 128 + rl;
      bSrc[h][j] = W1t + (size_t)e * HID * DIM + (size_t)brow * DIM + cs * 8;
    }

  f32x4 acc[2][2][4][2] = {};
  bf16x8 af[4][2], bf0[2][2], bf1[2][2];
  KLOOP(DIM / BK);

  // epilogue: + b1, exact gelu, bf16 store
#pragma unroll
  for (int BH_ = 0; BH_ < 2; ++BH_)
#pragma unroll
  for (int ni = 0; ni < 2; ++ni) {
    int col = nt * 256 + BH_ * 128 + wn * 32 + ni * 16 + l16;
    float bv = b1[e * HID + col];
#pragma unroll
    for (int AH_ = 0; AH_ < 2; ++AH_)
#pragma unroll
    for (int mi = 0; mi < 4; ++mi) {
      int r = row0 + AH_ * 128 + wm * 64 + mi * 16 + qr * 4;
#pragma unroll
      for (int j = 0; j < 4; ++j) {
        float v = acc[AH_][BH_][mi][ni][j] + bv;
        float g2 = 0.5f * v * (1.0f + erff(v * 0.70710678118654752f));
        Hb[(size_t)(r + j) * HID + col] = (bf16_t)g2;
      }
    }
  }
}

// ---------------- GEMM2: out[tok] += w * (Hb @ W2t^T + b2) ----------------
__global__ __launch_bounds__(512, 2) void gemm2_kernel(
    const bf16_t* __restrict__ Hb, const bf16_t* __restrict__ W2t,
    const float* __restrict__ b2, const int* __restrict__ ptok,
    const float* __restrict__ pw, const int* __restrict__ meta,
    float* __restrict__ out) {
  __shared__ __align__(16) char lds[163840];
  GEMM_PRE();
  // chunked XCD swizzle, mt-major (Hb streamed once; W2t via L3)
  int b = blockIdx.x;                       // 544 blocks
  int g = (b & 7) * 68 + (b >> 3);
  const int mt = g >> 2, nt = g & 3;
  const int row0 = mt * 256;
  const int* seg = meta + 16;
  int e = 0;
#pragma unroll
  for (int k = 1; k < NE; ++k) if (row0 >= seg[k]) e = k;
  if (row0 - seg[e] >= meta[e]) return;

  const bf16_t* aSrc[2][2];
  const bf16_t* bSrc[2][2];
#pragma unroll
  for (int h = 0; h < 2; ++h)
#pragma unroll
    for (int j = 0; j < 2; ++j) {
      int idx = j * 512 + tid;
      int rl = idx >> 3, c = idx & 7;
      int cs = c ^ (rl & 7);
      aSrc[h][j] = Hb + (size_t)(row0 + h * 128 + rl) * HID + cs * 8;
      int brow = nt * 256 + h * 128 + rl;
      bSrc[h][j] = W2t + (size_t)e * DIM * HID + (size_t)brow * HID + cs * 8;
    }

  f32x4 acc[2][2][4][2] = {};
  bf16x8 af[4][2], bf0[2][2], bf1[2][2];
  KLOOP(HID / BK);

  // epilogue: gather-combine with atomics
  float bv2[2][2];
#pragma unroll
  for (int BH_ = 0; BH_ < 2; ++BH_)
#pragma unroll
  for (int ni = 0; ni < 2; ++ni)
    bv2[BH_][ni] = b2[e * DIM + nt * 256 + BH_ * 128 + wn * 32 + ni * 16 + l16];

#pragma unroll
  for (int AH_ = 0; AH_ < 2; ++AH_)
#pragma unroll
  for (int mi = 0; mi < 4; ++mi) {
    int r = row0 + AH_ * 128 + wm * 64 + mi * 16 + qr * 4;
    int tk[4]; float wv[4];
#pragma unroll
    for (int j = 0; j < 4; ++j) { tk[j] = ptok[r + j]; wv[j] = pw[r + j]; }
#pragma unroll
    for (int BH_ = 0; BH_ < 2; ++BH_)
#pragma unroll
    for (int ni = 0; ni < 2; ++ni) {
      int col = nt * 256 + BH_ * 128 + wn * 32 + ni * 16 + l16;
#pragma unroll
      for (int j = 0; j < 4; ++j) {
        if (tk[j] >= 0)
          atomicAdd(out + (size_t)tk[j] * DIM + col,
                    wv[j] * (acc[AH_][BH_][mi][ni][j] + bv2[BH_][ni]));
      }
    }
  }
}

extern "C" void kernel_launch(void* const* d_in, const int* in_sizes, int n_in,
                              void* d_out, int out_size, void* d_ws, size_t ws_size,
                              hipStream_t stream) {
  const float* x    = (const float*)d_in[0];
  const float* rw   = (const float*)d_in[1];
  const float* w1   = (const float*)d_in[2];
  const float* b1   = (const float*)d_in[3];
  const float* w2   = (const float*)d_in[4];
  const float* b2   = (const float*)d_in[5];
  const float* bias = (const float*)d_in[6];
  float* out    = (float*)d_out;
  float* logits = out + (size_t)T_TOK * DIM;

  // workspace layout (bytes). W1t/W2t OVERLAY (transpose w2 after gemm1).
  const size_t XB_OFF = 0;                         // bf16 [T][D]      33,554,432
  const size_t WT_OFF = 33554432;                  // bf16 [E][*][*]   67,108,864 (shared)
  const size_t HB_OFF = 100663296;                 // bf16 [NSLOT][H] 285,212,672
  const size_t PT_OFF = 385875968;                 // int  [NSLOT]
  const size_t PW_OFF = 386015232;                 // f32  [NSLOT]
  const size_t TE_OFF = 386154496;                 // int  [T*2]
  const size_t TW_OFF = 386285568;                 // f32  [T*2]
  const size_t MT_OFF = 386416640;                 // int  [32]
  const size_t WS_NEEDED = MT_OFF + 128;
  if (ws_size < WS_NEEDED) return;

  char* ws = (char*)d_ws;
  bf16_t* Xb  = (bf16_t*)(ws + XB_OFF);
  bf16_t* Wt  = (bf16_t*)(ws + WT_OFF);
  bf16_t* Hb  = (bf16_t*)(ws + HB_OFF);
  int*    ptok= (int*)  (ws + PT_OFF);
  float*  pwv = (float*)(ws + PW_OFF);
  int*    te  = (int*)  (ws + TE_OFF);
  float*  tw  = (float*)(ws + TW_OFF);
  int*    meta= (int*)  (ws + MT_OFF);

  init_meta_kernel<<<NSLOT / 256, 256, 0, stream>>>(ptok, meta);
  router_kernel<<<T_TOK / 4, 256, 0, stream>>>(x, rw, logits, meta, te, tw, Xb);
  scan_kernel<<<1, 64, 0, stream>>>(meta);
  scatter_kernel<<<T_TOK / 256, 256, 0, stream>>>(te, tw, meta, ptok, pwv);
  // W1 transpose: [E][D][H] -> [E][H][D]
  transpose_cvt_kernel<<<dim3(HID / 64, DIM / 64, NE), 256, 0, stream>>>(w1, Wt, DIM, HID);
  init_out_kernel<<<2048, 256, 0, stream>>>(out, bias);
  gemm1_kernel<<<2176, 512, 0, stream>>>(Xb, Wt, b1, ptok, meta, Hb);
  // W2 transpose into the SAME buffer (gemm1 done reading W1t; stream serializes)
  transpose_cvt_kernel<<<dim3(DIM / 64, HID / 64, NE), 256, 0, stream>>>(w2, Wt, HID, DIM);
  gemm2_kernel<<<544, 512, 0, stream>>>(Hb, Wt, b2, ptok, pwv, meta, out);
}

// Round 4
// 1399.038 us; speedup vs baseline: 1.3603x; 1.0304x over previous
//
#include <hip/hip_runtime.h>
#include <hip/hip_bf16.h>
#include <cstdint>
#include <cstddef>

#define T_TOK 16384
#define DIM   1024
#define HID   4096
#define NE    8
#define NSLOT 34816   /* 32768 + 8*256 max padded slots (256-aligned segments) */
#define BK 64

typedef __bf16 bf16_t;
typedef __bf16 bf16x8 __attribute__((ext_vector_type(8)));
typedef __bf16 bf16x4v __attribute__((ext_vector_type(4)));
typedef float  f32x4  __attribute__((ext_vector_type(4)));

__device__ __forceinline__ void gload_lds16(const void* g, const void* l) {
  __builtin_amdgcn_global_load_lds(
      (const __attribute__((address_space(1))) uint32_t*)(uintptr_t)g,
      (__attribute__((address_space(3))) uint32_t*)(uint32_t)(uintptr_t)l,
      16, 0, 0);
}

// meta layout (ints): [0..7]=counts, [8..15]=cursor, [16..24]=seg_base(9)

__global__ __launch_bounds__(256) void init_meta_kernel(int* __restrict__ ptok,
                                                        int* __restrict__ meta) {
  int i = blockIdx.x * 256 + threadIdx.x;
  if (i < NSLOT) ptok[i] = -1;
  if (i < 16) meta[i] = 0;
}

// router + fused f32->bf16 conversion of x into Xb (vectorized 32B/lane)
__global__ __launch_bounds__(256) void router_kernel(
    const float* __restrict__ x, const float* __restrict__ rw,
    float* __restrict__ logits, int* __restrict__ meta,
    int* __restrict__ te, float* __restrict__ tw, bf16_t* __restrict__ Xb) {
  const int lane = threadIdx.x & 63;
  const int t = blockIdx.x * 4 + (threadIdx.x >> 6);
  const float* xr = x + (size_t)t * DIM;
  float acc[NE] = {0.f,0.f,0.f,0.f,0.f,0.f,0.f,0.f};
#pragma unroll
  for (int j = 0; j < 2; ++j) {
    int d0 = j * 512 + lane * 8;
    float4 a = *(const float4*)(xr + d0);
    float4 b = *(const float4*)(xr + d0 + 4);
    bf16x8 o = { (bf16_t)a.x, (bf16_t)a.y, (bf16_t)a.z, (bf16_t)a.w,
                 (bf16_t)b.x, (bf16_t)b.y, (bf16_t)b.z, (bf16_t)b.w };
    *(bf16x8*)(Xb + (size_t)t * DIM + d0) = o;
    float xs[8] = {a.x, a.y, a.z, a.w, b.x, b.y, b.z, b.w};
#pragma unroll
    for (int k = 0; k < 8; ++k) {
      float4 wa = *(const float4*)(rw + (size_t)(d0 + k) * NE);
      float4 wb = *(const float4*)(rw + (size_t)(d0 + k) * NE + 4);
      acc[0] += xs[k] * wa.x; acc[1] += xs[k] * wa.y;
      acc[2] += xs[k] * wa.z; acc[3] += xs[k] * wa.w;
      acc[4] += xs[k] * wb.x; acc[5] += xs[k] * wb.y;
      acc[6] += xs[k] * wb.z; acc[7] += xs[k] * wb.w;
    }
  }
#pragma unroll
  for (int off = 32; off; off >>= 1) {
#pragma unroll
    for (int e = 0; e < NE; ++e) acc[e] += __shfl_down(acc[e], off);
  }
  if (lane == 0) {
    float m = acc[0];
#pragma unroll
    for (int e = 1; e < NE; ++e) m = fmaxf(m, acc[e]);
    float p[NE]; float s = 0.f;
#pragma unroll
    for (int e = 0; e < NE; ++e) { p[e] = expf(acc[e] - m); s += p[e]; }
    float inv = 1.0f / s;
    int e0 = 0;
#pragma unroll
    for (int e = 1; e < NE; ++e) if (p[e] > p[e0]) e0 = e;
    int e1 = (e0 == 0) ? 1 : 0;
#pragma unroll
    for (int e = 0; e < NE; ++e) if (e != e0 && p[e] > p[e1]) e1 = e;
#pragma unroll
    for (int e = 0; e < NE; ++e) logits[(size_t)t * NE + e] = acc[e];
    te[2 * t]     = e0;  te[2 * t + 1] = e1;
    tw[2 * t]     = p[e0] * inv;
    tw[2 * t + 1] = p[e1] * inv;
    atomicAdd(&meta[e0], 1);
    atomicAdd(&meta[e1], 1);
  }
}

__global__ void scan_kernel(int* __restrict__ meta) {
  if (threadIdx.x == 0 && blockIdx.x == 0) {
    int* seg = meta + 16;
    seg[0] = 0;
    for (int e = 0; e < NE; ++e) {
      seg[e + 1] = seg[e] + ((meta[e] + 255) / 256) * 256;
      meta[8 + e] = 0;
    }
  }
}

__global__ __launch_bounds__(256) void scatter_kernel(
    const int* __restrict__ te, const float* __restrict__ tw,
    int* __restrict__ meta, int* __restrict__ ptok, float* __restrict__ pw) {
  int t = blockIdx.x * 256 + threadIdx.x;
#pragma unroll
  for (int k = 0; k < 2; ++k) {
    int e = te[2 * t + k];
    int pos = meta[16 + e] + atomicAdd(&meta[8 + e], 1);
    ptok[pos] = t;
    pw[pos] = tw[2 * t + k];
  }
}

// src: float [E][R][C]  ->  dst: bf16 [E][C][R]   (64x64 tiles, 256 thr, vectorized)
__global__ __launch_bounds__(256) void transpose_cvt_kernel(
    const float* __restrict__ src, bf16_t* __restrict__ dst, int R, int C) {
  __shared__ bf16_t tile[64][68];
  int e = blockIdx.z;
  int c0 = blockIdx.x * 64, r0 = blockIdx.y * 64;
  const float* s = src + (size_t)e * R * C;
  bf16_t* d = dst + (size_t)e * R * C;
  int tx = threadIdx.x & 15, ty = threadIdx.x >> 4;
#pragma unroll
  for (int i = 0; i < 4; ++i) {
    int r = ty + i * 16;
    float4 v = *(const float4*)(s + (size_t)(r0 + r) * C + c0 + tx * 4);
    tile[r][tx * 4 + 0] = (bf16_t)v.x;
    tile[r][tx * 4 + 1] = (bf16_t)v.y;
    tile[r][tx * 4 + 2] = (bf16_t)v.z;
    tile[r][tx * 4 + 3] = (bf16_t)v.w;
  }
  __syncthreads();
#pragma unroll
  for (int i = 0; i < 4; ++i) {
    int cc = ty + i * 16;
    bf16x4v o = { tile[tx * 4 + 0][cc], tile[tx * 4 + 1][cc],
                  tile[tx * 4 + 2][cc], tile[tx * 4 + 3][cc] };
    *(bf16x4v*)(d + (size_t)(c0 + cc) * R + r0 + tx * 4) = o;
  }
}

__global__ __launch_bounds__(256) void init_out_kernel(float* __restrict__ out,
                                                       const float* __restrict__ bias) {
  const int n4 = T_TOK * DIM / 4;
  for (int i = blockIdx.x * 256 + threadIdx.x; i < n4; i += gridDim.x * 256) {
    ((float4*)out)[i] = ((const float4*)bias)[i & 255];
  }
}

// ============ 256x256 8-wave pipelined GEMM: A ring 3-deep, B 2-deep ============
// LDS 160KiB: A stage s at s*32768 (s=0..2), halves +h*16384.
//             B stage p at 98304 + p*32768 (p=0..1), halves +h*16384.
// Swizzle (verified r1-r3): LDS (row, chunk c) holds source chunk c^(row&7).
// Scheduling: NO sched_barrier / explicit lgkmcnt — compiler emits fine-grained
// lgkmcnt between ds_read and dependent MFMA (m97 asm evidence). One s_barrier
// per region; counted vmcnt(6) twice per K-tile (issue->deadline >= 3 regions,
// hand-verified hazard-free under arbitrary intra-region reordering).

#define GEMM_PRE()                                                              \
  const int tid = threadIdx.x;                                                  \
  const int lane = tid & 63;                                                    \
  const int wave = tid >> 6;                                                    \
  const int wm = wave >> 2, wn = wave & 3;                                      \
  const int qr = lane >> 4, l16 = lane & 15;                                    \
  const uint32_t aRd0 = (wm * 64 + l16) * 128 + ((qr ^ (l16 & 7)) * 16);        \
  const uint32_t aRd1 = (wm * 64 + l16) * 128 + (((4 + qr) ^ (l16 & 7)) * 16);  \
  const uint32_t bRd0 = (wn * 32 + l16) * 128 + ((qr ^ (l16 & 7)) * 16);        \
  const uint32_t bRd1 = (wn * 32 + l16) * 128 + (((4 + qr) ^ (l16 & 7)) * 16);  \
  uint32_t aB0 = 0, aB1 = 32768, aB2 = 65536;

#define STAGE_Ax(BASE, H, KT) {                                                 \
  const char* _d = lds + (BASE) + (H) * 16384 + tid * 16;                       \
  gload_lds16(aSrc[H][0] + (size_t)(KT) * BK, _d);                              \
  gload_lds16(aSrc[H][1] + (size_t)(KT) * BK, _d + 8192); }

#define STAGE_Bx(H, P2, KT) {                                                   \
  const char* _d = lds + 98304 + (P2) * 32768 + (H) * 16384 + tid * 16;         \
  gload_lds16(bSrc[H][0] + (size_t)(KT) * BK, _d);                              \
  gload_lds16(bSrc[H][1] + (size_t)(KT) * BK, _d + 8192); }

#define LOAD_AFx(AH) {                                                          \
  const char* _p = lds + aB0 + (AH) * 16384;                                    \
  _Pragma("unroll")                                                             \
  for (int mi = 0; mi < 4; ++mi) {                                              \
    af[mi][0] = *(const bf16x8*)(_p + aRd0 + mi * 2048);                        \
    af[mi][1] = *(const bf16x8*)(_p + aRd1 + mi * 2048); } }

#define LOAD_BFx(BH, BF, P) {                                                   \
  const char* _p = lds + 98304 + (P) * 32768 + (BH) * 16384;                    \
  _Pragma("unroll")                                                             \
  for (int ni = 0; ni < 2; ++ni) {                                              \
    BF[ni][0] = *(const bf16x8*)(_p + bRd0 + ni * 2048);                        \
    BF[ni][1] = *(const bf16x8*)(_p + bRd1 + ni * 2048); } }

#define MFMA_PH(AH, BH, BF)                                                     \
  __builtin_amdgcn_s_setprio(1);                                                \
  _Pragma("unroll")                                                             \
  for (int mi = 0; mi < 4; ++mi)                                                \
  _Pragma("unroll")                                                             \
  for (int ni = 0; ni < 2; ++ni) {                                              \
    acc[AH][BH][mi][ni] = __builtin_amdgcn_mfma_f32_16x16x32_bf16(              \
        af[mi][0], BF[ni][0], acc[AH][BH][mi][ni], 0, 0, 0);                    \
    acc[AH][BH][mi][ni] = __builtin_amdgcn_mfma_f32_16x16x32_bf16(              \
        af[mi][1], BF[ni][1], acc[AH][BH][mi][ni], 0, 0, 0);                    \
  }                                                                             \
  __builtin_amdgcn_s_setprio(0);

#define TILE_BODY(TT, P, NT)                                                    \
  {                                                                             \
    const int kt1 = ((TT) + 1 < (NT)) ? (TT) + 1 : (NT) - 1;                    \
    const int kt2 = ((TT) + 2 < (NT)) ? (TT) + 2 : (NT) - 1;                    \
    /* R1: quadrant (A0,B0) */                                                  \
    LOAD_AFx(0);                                                                \
    LOAD_BFx(0, bf0, P);                                                        \
    STAGE_Bx(0, (P) ^ 1, kt1);                                                  \
    MFMA_PH(0, 0, bf0);                                                         \
    asm volatile("s_waitcnt vmcnt(6)" ::: "memory");                            \
    __builtin_amdgcn_s_barrier();                                               \
    /* R2: quadrant (A0,B1) */                                                  \
    LOAD_BFx(1, bf1, P);                                                        \
    STAGE_Bx(1, (P) ^ 1, kt1);                                                  \
    MFMA_PH(0, 1, bf1);                                                         \
    __builtin_amdgcn_s_barrier();                                               \
    /* R3: quadrant (A1,B0) */                                                  \
    LOAD_AFx(1);                                                                \
    STAGE_Ax(aB2, 0, kt2);                                                      \
    MFMA_PH(1, 0, bf0);                                                         \
    __builtin_amdgcn_s_barrier();                                               \
    /* R4: quadrant (A1,B1) */                                                  \
    STAGE_Ax(aB2, 1, kt2);                                                      \
    MFMA_PH(1, 1, bf1);                                                         \
    asm volatile("s_waitcnt vmcnt(6)" ::: "memory");                            \
    __builtin_amdgcn_s_barrier();                                               \
    uint32_t _tmp = aB0; aB0 = aB1; aB1 = aB2; aB2 = _tmp;                      \
  }

#define KLOOP(NT)                                                               \
  {                                                                             \
    const int ktp = 1 < (NT) ? 1 : 0;                                           \
    STAGE_Ax(aB0, 0, 0); STAGE_Ax(aB0, 1, 0);                                   \
    STAGE_Bx(0, 0, 0); STAGE_Bx(1, 0, 0);                                       \
    STAGE_Ax(aB1, 0, ktp); STAGE_Ax(aB1, 1, ktp);                               \
    asm volatile("s_waitcnt vmcnt(4)" ::: "memory");                            \
    __builtin_amdgcn_s_barrier();                                               \
  }                                                                             \
  for (int t = 0; t < (NT); t += 2) {                                           \
    TILE_BODY(t, 0, NT);                                                        \
    TILE_BODY(t + 1, 1, NT);                                                    \
  }

// ---------------- GEMM1: Hb = gelu(gather(Xb) @ W1t^T + b1) ----------------
__global__ __launch_bounds__(512, 2) void gemm1_kernel(
    const bf16_t* __restrict__ Xb, const bf16_t* __restrict__ W1t,
    const float* __restrict__ b1, const int* __restrict__ ptok,
    const int* __restrict__ meta, bf16_t* __restrict__ Hb) {
  __shared__ __align__(16) char lds[163840];
  GEMM_PRE();
  // chunked XCD swizzle, mt-major within chunk (round-2 mapping: FETCH 328MB)
  int b = blockIdx.x;                       // 2176 blocks
  int g = (b & 7) * 272 + (b >> 3);
  const int mt = g >> 4, nt = g & 15;
  const int row0 = mt * 256;
  const int* seg = meta + 16;
  int e = 0;
#pragma unroll
  for (int k = 1; k < NE; ++k) if (row0 >= seg[k]) e = k;
  if (row0 - seg[e] >= meta[e]) return;

  const bf16_t* aSrc[2][2];
  const bf16_t* bSrc[2][2];
#pragma unroll
  for (int h = 0; h < 2; ++h)
#pragma unroll
    for (int j = 0; j < 2; ++j) {
      int idx = j * 512 + tid;
      int rl = idx >> 3, c = idx & 7;
      int cs = c ^ (rl & 7);
      int tok = ptok[row0 + h * 128 + rl];
      if (tok < 0) tok = 0;
      aSrc[h][j] = Xb + (size_t)tok * DIM + cs * 8;
      int brow = nt * 256 + h * 128 + rl;
      bSrc[h][j] = W1t + (size_t)e * HID * DIM + (size_t)brow * DIM + cs * 8;
    }

  f32x4 acc[2][2][4][2] = {};
  bf16x8 af[4][2], bf0[2][2], bf1[2][2];
  KLOOP(DIM / BK);

  // epilogue: + b1, exact gelu, bf16 store
#pragma unroll
  for (int BH_ = 0; BH_ < 2; ++BH_)
#pragma unroll
  for (int ni = 0; ni < 2; ++ni) {
    int col = nt * 256 + BH_ * 128 + wn * 32 + ni * 16 + l16;
    float bv = b1[e * HID + col];
#pragma unroll
    for (int AH_ = 0; AH_ < 2; ++AH_)
#pragma unroll
    for (int mi = 0; mi < 4; ++mi) {
      int r = row0 + AH_ * 128 + wm * 64 + mi * 16 + qr * 4;
#pragma unroll
      for (int j = 0; j < 4; ++j) {
        float v = acc[AH_][BH_][mi][ni][j] + bv;
        float g2 = 0.5f * v * (1.0f + erff(v * 0.70710678118654752f));
        Hb[(size_t)(r + j) * HID + col] = (bf16_t)g2;
      }
    }
  }
}

// ---------------- GEMM2: out[tok] += w * (Hb @ W2t^T + b2) ----------------
__global__ __launch_bounds__(512, 2) void gemm2_kernel(
    const bf16_t* __restrict__ Hb, const bf16_t* __restrict__ W2t,
    const float* __restrict__ b2, const int* __restrict__ ptok,
    const float* __restrict__ pw, const int* __restrict__ meta,
    float* __restrict__ out) {
  __shared__ __align__(16) char lds[163840];
  GEMM_PRE();
  // chunked XCD swizzle, mt-major (Hb streamed once; W2t via L3)
  int b = blockIdx.x;                       // 544 blocks
  int g = (b & 7) * 68 + (b >> 3);
  const int mt = g >> 2, nt = g & 3;
  const int row0 = mt * 256;
  const int* seg = meta + 16;
  int e = 0;
#pragma unroll
  for (int k = 1; k < NE; ++k) if (row0 >= seg[k]) e = k;
  if (row0 - seg[e] >= meta[e]) return;

  const bf16_t* aSrc[2][2];
  const bf16_t* bSrc[2][2];
#pragma unroll
  for (int h = 0; h < 2; ++h)
#pragma unroll
    for (int j = 0; j < 2; ++j) {
      int idx = j * 512 + tid;
      int rl = idx >> 3, c = idx & 7;
      int cs = c ^ (rl & 7);
      aSrc[h][j] = Hb + (size_t)(row0 + h * 128 + rl) * HID + cs * 8;
      int brow = nt * 256 + h * 128 + rl;
      bSrc[h][j] = W2t + (size_t)e * DIM * HID + (size_t)brow * HID + cs * 8;
    }

  f32x4 acc[2][2][4][2] = {};
  bf16x8 af[4][2], bf0[2][2], bf1[2][2];
  KLOOP(HID / BK);

  // epilogue: gather-combine with atomics
  float bv2[2][2];
#pragma unroll
  for (int BH_ = 0; BH_ < 2; ++BH_)
#pragma unroll
  for (int ni = 0; ni < 2; ++ni)
    bv2[BH_][ni] = b2[e * DIM + nt * 256 + BH_ * 128 + wn * 32 + ni * 16 + l16];

#pragma unroll
  for (int AH_ = 0; AH_ < 2; ++AH_)
#pragma unroll
  for (int mi = 0; mi < 4; ++mi) {
    int r = row0 + AH_ * 128 + wm * 64 + mi * 16 + qr * 4;
    int tk[4]; float wv[4];
#pragma unroll
    for (int j = 0; j < 4; ++j) { tk[j] = ptok[r + j]; wv[j] = pw[r + j]; }
#pragma unroll
    for (int BH_ = 0; BH_ < 2; ++BH_)
#pragma unroll
    for (int ni = 0; ni < 2; ++ni) {
      int col = nt * 256 + BH_ * 128 + wn * 32 + ni * 16 + l16;
#pragma unroll
      for (int j = 0; j < 4; ++j) {
        if (tk[j] >= 0)
          atomicAdd(out + (size_t)tk[j] * DIM + col,
                    wv[j] * (acc[AH_][BH_][mi][ni][j] + bv2[BH_][ni]));
      }
    }
  }
}

extern "C" void kernel_launch(void* const* d_in, const int* in_sizes, int n_in,
                              void* d_out, int out_size, void* d_ws, size_t ws_size,
                              hipStream_t stream) {
  const float* x    = (const float*)d_in[0];
  const float* rw   = (const float*)d_in[1];
  const float* w1   = (const float*)d_in[2];
  const float* b1   = (const float*)d_in[3];
  const float* w2   = (const float*)d_in[4];
  const float* b2   = (const float*)d_in[5];
  const float* bias = (const float*)d_in[6];
  float* out    = (float*)d_out;
  float* logits = out + (size_t)T_TOK * DIM;

  // workspace layout (bytes). W1t/W2t OVERLAY (transpose w2 after gemm1).
  const size_t XB_OFF = 0;                         // bf16 [T][D]      33,554,432
  const size_t WT_OFF = 33554432;                  // bf16 [E][*][*]   67,108,864 (shared)
  const size_t HB_OFF = 100663296;                 // bf16 [NSLOT][H] 285,212,672
  const size_t PT_OFF = 385875968;                 // int  [NSLOT]
  const size_t PW_OFF = 386015232;                 // f32  [NSLOT]
  const size_t TE_OFF = 386154496;                 // int  [T*2]
  const size_t TW_OFF = 386285568;                 // f32  [T*2]
  const size_t MT_OFF = 386416640;                 // int  [32]
  const size_t WS_NEEDED = MT_OFF + 128;
  if (ws_size < WS_NEEDED) return;

  char* ws = (char*)d_ws;
  bf16_t* Xb  = (bf16_t*)(ws + XB_OFF);
  bf16_t* Wt  = (bf16_t*)(ws + WT_OFF);
  bf16_t* Hb  = (bf16_t*)(ws + HB_OFF);
  int*    ptok= (int*)  (ws + PT_OFF);
  float*  pwv = (float*)(ws + PW_OFF);
  int*    te  = (int*)  (ws + TE_OFF);
  float*  tw  = (float*)(ws + TW_OFF);
  int*    meta= (int*)  (ws + MT_OFF);

  init_meta_kernel<<<NSLOT / 256, 256, 0, stream>>>(ptok, meta);
  router_kernel<<<T_TOK / 4, 256, 0, stream>>>(x, rw, logits, meta, te, tw, Xb);
  scan_kernel<<<1, 64, 0, stream>>>(meta);
  scatter_kernel<<<T_TOK / 256, 256, 0, stream>>>(te, tw, meta, ptok, pwv);
  // W1 transpose: [E][D][H] -> [E][H][D]
  transpose_cvt_kernel<<<dim3(HID / 64, DIM / 64, NE), 256, 0, stream>>>(w1, Wt, DIM, HID);
  init_out_kernel<<<2048, 256, 0, stream>>>(out, bias);
  gemm1_kernel<<<2176, 512, 0, stream>>>(Xb, Wt, b1, ptok, meta, Hb);
  // W2 transpose into the SAME buffer (gemm1 done reading W1t; stream serializes)
  transpose_cvt_kernel<<<dim3(DIM / 64, HID / 64, NE), 256, 0, stream>>>(w2, Wt, HID, DIM);
  gemm2_kernel<<<544, 512, 0, stream>>>(Hb, Wt, b2, ptok, pwv, meta, out);
}